// Round 8
// baseline (444.189 us; speedup 1.0000x reference)
//
#include <hip/hip_runtime.h>

// SpectralConvLayer: per-scale linear (x+spectral)@Ws concat -> ragged MHA
// (no key-padding mask: padded keys contribute exp(0)=1 to denom) -> out-proj
// -> BatchNorm(batch stats) -> ReLU.
// Round 8: BM=64 tiles for all skinny GEMMs (2048/3072/1024 blocks) — these are
// latency-bound (R7: k_scale VALUBusy 5%, MfmaUtil 2%, occ 27%); smaller tiles
// double resident blocks/CU for TLP latency hiding.

typedef __attribute__((ext_vector_type(8))) short frag8;      // 8 bf16 (4 VGPR)
typedef __attribute__((ext_vector_type(4))) short frag4;      // 4 bf16 (2 VGPR)
typedef __attribute__((ext_vector_type(4))) float f32x4;
typedef __attribute__((ext_vector_type(8))) unsigned short ushort8;
typedef __attribute__((ext_vector_type(2))) unsigned int uint2e;

#define NN 32768
#define NB 64
#define CIN 256
#define COUT 256
#define NHEAD 8
#define HD 32

#define SBM 64   // GEMM M-tile (latency-bound skinny GEMMs want small tiles)
#define BK 64
#define LDK 72   // +8 shorts pad: breaks pow2 LDS strides
#define KT 128   // attention key-tile (V staging)

#if __has_builtin(__builtin_amdgcn_mfma_f32_16x16x16bf16_1k)
#define HAS_MFMA16 1
#else
#define HAS_MFMA16 0
#endif

__device__ inline unsigned short f2bf(float f) {
  unsigned u = __builtin_bit_cast(unsigned, f);
  u += 0x7FFFu + ((u >> 16) & 1u);          // RNE
  return (unsigned short)(u >> 16);
}
__device__ inline float bf2f(unsigned short h) {
  return __builtin_bit_cast(float, (unsigned)h << 16);
}
__device__ inline unsigned pack2bf(float a, float b) {
  return (unsigned)f2bf(a) | ((unsigned)f2bf(b) << 16);
}

// ---------------- prep (fp32->bf16 weights, Ws transposed) + batch boundaries ----
__global__ void k_prep(const float* __restrict__ Ws, const float* __restrict__ Win,
                       const float* __restrict__ Wout, const int* __restrict__ batch,
                       unsigned short* __restrict__ wst, unsigned short* __restrict__ winb,
                       unsigned short* __restrict__ woutb, int* __restrict__ meta) {
  int tid = blockIdx.x * 256 + threadIdx.x;
  if (tid < NN) {  // boundary detection on sorted batch -> starts
    int v = batch[tid];
    int prev = (tid == 0) ? -1 : batch[tid - 1];
    for (int bb = prev + 1; bb <= v; ++bb) meta[NB + bb] = tid;
  }
  if (tid < 4 * 64 * 256) {
    int s = tid >> 14, rem = tid & 16383, o = rem >> 8, i = rem & 255;
    wst[tid] = f2bf(Ws[((s * 256) + i) * 64 + o]);
  } else if (tid < 4 * 64 * 256 + 768 * 256) {
    int t2 = tid - 4 * 64 * 256;
    winb[t2] = f2bf(Win[t2]);
  } else if (tid < 4 * 64 * 256 + 768 * 256 + 256 * 256) {
    int t3 = tid - (4 * 64 * 256 + 768 * 256);
    woutb[t3] = f2bf(Wout[t3]);
  }
}
__global__ void k_meta2(int* __restrict__ meta) {
  __shared__ int mx[NB];
  int b = threadIdx.x;  // 64 threads
  int s = meta[NB + b];
  int e = (b == 63) ? NN : meta[NB + b + 1];
  meta[b] = e - s;
  mx[b] = e - s;
  __syncthreads();
  if (b == 0) {
    int m = 0;
    for (int j = 0; j < NB; ++j) m = max(m, mx[j]);
    meta[2 * NB] = m;
  }
}

// ---------------- shared GEMM pieces ----------------
// A-frag(16x16x32): lane(m=l&15,q=l>>4) holds A[m][q*8+j]
// B-frag          : lane(n=l&15,q)      holds B[q*8+j][n] = Bt[n][q*8+j]
// C/D             : lane holds D[q*4+reg][l&15]     (measured m89/m91)
// Wave w covers MT m-tiles starting at row (w*MT)*16.
template <int MT, int NT>
__device__ inline void mfma_tile(const unsigned short (*As)[LDK],
                                 const unsigned short (*Bs)[LDK],
                                 f32x4 acc[MT][NT], int wave, int lane) {
  int m16 = lane & 15, quad = lane >> 4;
#pragma unroll
  for (int kk = 0; kk < 2; ++kk) {
    frag8 a[MT], b[NT];
#pragma unroll
    for (int mi = 0; mi < MT; ++mi)
      a[mi] = *(const frag8*)&As[(wave * MT + mi) * 16 + m16][kk * 32 + quad * 8];
#pragma unroll
    for (int ni = 0; ni < NT; ++ni)
      b[ni] = *(const frag8*)&Bs[ni * 16 + m16][kk * 32 + quad * 8];
#pragma unroll
    for (int mi = 0; mi < MT; ++mi)
#pragma unroll
      for (int ni = 0; ni < NT; ++ni)
        acc[mi][ni] = __builtin_amdgcn_mfma_f32_16x16x32_bf16(a[mi], b[ni], acc[mi][ni], 0, 0, 0);
  }
}

__device__ inline void stage_B64(const unsigned short* __restrict__ Wt, int c0, int k0,
                                 unsigned short (*Bs)[LDK], int t) {
  int n = t & 63, seg = t >> 6;
  const unsigned short* src = Wt + (size_t)(c0 + n) * 256 + k0 + seg * 16;
  uint4 v0 = *(const uint4*)src;
  uint4 v1 = *(const uint4*)(src + 8);
  *(uint4*)&Bs[n][seg * 16] = v0;
  *(uint4*)&Bs[n][seg * 16 + 8] = v1;
}

__device__ inline void stage_B128(const unsigned short* __restrict__ Wt, int c0, int k0,
                                  unsigned short (*Bs)[LDK], int t) {
  int n = t >> 1, half = t & 1;
  const unsigned short* src = Wt + (size_t)(c0 + n) * 256 + k0 + half * 32;
#pragma unroll
  for (int i = 0; i < 4; ++i) {
    uint4 v = *(const uint4*)(src + i * 8);
    *(uint4*)&Bs[n][half * 32 + i * 8] = v;
  }
}

// A staging for 64-row tiles: thread covers 16 shorts
__device__ inline void stage_A64(const unsigned short* __restrict__ A, int r0, int k0,
                                 unsigned short (*As)[LDK], int t) {
  int r = t >> 2, seg = t & 3;
  const unsigned short* src = A + (size_t)(r0 + r) * 256 + k0 + seg * 16;
  uint4 v0 = *(const uint4*)src;
  uint4 v1 = *(const uint4*)(src + 8);
  *(uint4*)&As[r][seg * 16] = v0;
  *(uint4*)&As[r][seg * 16 + 8] = v1;
}

// ---------------- scale-linear: h[n, s*64+o] = (x+spec_s)[n,:] @ Ws[s] + bs ----------------
__global__ __launch_bounds__(256) void k_scale(const float* __restrict__ x,
                                               const float* __restrict__ spec,
                                               const unsigned short* __restrict__ wst,
                                               const float* __restrict__ bs,
                                               unsigned short* __restrict__ h) {
  __shared__ unsigned short As[SBM][LDK];
  __shared__ unsigned short Bs[64][LDK];
  int t = threadIdx.x, lane = t & 63, wave = t >> 6;
  int r0 = blockIdx.x * SBM, s = blockIdx.y;
  f32x4 z = {0.f, 0.f, 0.f, 0.f};
  f32x4 acc[1][4];
#pragma unroll
  for (int ni = 0; ni < 4; ++ni) acc[0][ni] = z;

  const float* sb = spec + (size_t)s * NN * CIN;
  for (int k0 = 0; k0 < CIN; k0 += BK) {
    {  // fused A staging: fp32 x + spectral -> bf16 LDS (64 rows, 16 floats/thread)
      int r = t >> 2, seg = t & 3;
      const float* xs = x + (size_t)(r0 + r) * CIN + k0 + seg * 16;
      const float* ss = sb + (size_t)(r0 + r) * CIN + k0 + seg * 16;
#pragma unroll
      for (int i = 0; i < 4; ++i) {
        float4 xv = *(const float4*)(xs + i * 4);
        float4 sv = *(const float4*)(ss + i * 4);
        ushort4 o;
        o.x = f2bf(xv.x + sv.x); o.y = f2bf(xv.y + sv.y);
        o.z = f2bf(xv.z + sv.z); o.w = f2bf(xv.w + sv.w);
        *(ushort4*)&As[r][seg * 16 + i * 4] = o;
      }
    }
    stage_B64(wst + (size_t)s * 64 * 256, 0, k0, Bs, t);
    __syncthreads();
    mfma_tile<1, 4>(As, Bs, acc, wave, lane);
    __syncthreads();
  }
  int m16 = lane & 15, quad = lane >> 4;
#pragma unroll
  for (int ni = 0; ni < 4; ++ni) {
    int col = ni * 16 + m16;
    float bias = bs[s * 64 + col];
#pragma unroll
    for (int r = 0; r < 4; ++r) {
      int row = r0 + wave * 16 + quad * 4 + r;
      h[(size_t)row * COUT + s * 64 + col] = f2bf(acc[0][ni][r] + bias);
    }
  }
}

// ------- bf16 GEMM, BM=64/BN=128; STATS fuses BatchNorm sum/sumsq reduction -------
template <int LDOUT, bool F32OUT, bool STATS>
__global__ __launch_bounds__(256) void k_lin(const unsigned short* __restrict__ A,
                                             const unsigned short* __restrict__ Wt,
                                             const float* __restrict__ bias,
                                             void* __restrict__ out,
                                             float* __restrict__ sums) {
  __shared__ unsigned short As[SBM][LDK];
  __shared__ unsigned short Bs[128][LDK];
  int t = threadIdx.x, lane = t & 63, wave = t >> 6;
  int r0 = blockIdx.x * SBM, c0 = blockIdx.y * 128;
  f32x4 z = {0.f, 0.f, 0.f, 0.f};
  f32x4 acc[1][8];
#pragma unroll
  for (int ni = 0; ni < 8; ++ni) acc[0][ni] = z;

  for (int k0 = 0; k0 < 256; k0 += BK) {
    stage_A64(A, r0, k0, As, t);
    stage_B128(Wt, c0, k0, Bs, t);
    __syncthreads();
    mfma_tile<1, 8>(As, Bs, acc, wave, lane);
    __syncthreads();
  }
  int m16 = lane & 15, quad = lane >> 4;
  float cs[8], cs2[8];
#pragma unroll
  for (int ni = 0; ni < 8; ++ni) { cs[ni] = 0.f; cs2[ni] = 0.f; }
#pragma unroll
  for (int ni = 0; ni < 8; ++ni) {
    int col = c0 + ni * 16 + m16;
    float bv = bias[col];
#pragma unroll
    for (int r = 0; r < 4; ++r) {
      int row = r0 + wave * 16 + quad * 4 + r;
      float v = acc[0][ni][r] + bv;
      if constexpr (STATS) { cs[ni] += v; cs2[ni] += v * v; }
      if constexpr (F32OUT)
        ((float*)out)[(size_t)row * LDOUT + col] = v;
      else
        ((unsigned short*)out)[(size_t)row * LDOUT + col] = f2bf(v);
    }
  }
  if constexpr (STATS) {
#pragma unroll
    for (int ni = 0; ni < 8; ++ni) {
      float a = cs[ni], b2 = cs2[ni];
      a += __shfl_xor(a, 16); a += __shfl_xor(a, 32);
      b2 += __shfl_xor(b2, 16); b2 += __shfl_xor(b2, 32);
      if (quad == 0) {
        atomicAdd(&sums[c0 + ni * 16 + m16], a);
        atomicAdd(&sums[256 + c0 + ni * 16 + m16], b2);
      }
    }
  }
}

// ---------------- MFMA flash attention ----------------
// Block = (graph*8+head, qchunk of 128). 4 waves x 32 q-rows each.
// S^T = K*Q^T (swapped operands, same global fragments). Its C-layout
// (lane: q=m16, key=quad*4+r) IS the 16x16x16 A-fragment layout, so PV runs as
// 16x16x16 MFMAs with zero cross-lane data movement. Main chunks mask-free;
// only the final partial 32-chunk masks. Padded keys add exactly 1 -> +(M-c).
__global__ __launch_bounds__(256) void k_attn_mfma(const unsigned short* __restrict__ qkv,
                                                   const int* __restrict__ meta,
                                                   unsigned short* __restrict__ ctx) {
  int b = blockIdx.x >> 3, head = blockIdx.x & 7;
  int c = meta[b], st = meta[NB + b], M = meta[2 * NB];
  int q0 = blockIdx.y * 128;
  if (q0 >= c) return;

  __shared__ unsigned short Vt[32][KT + 8];   // V^T tile [d][key]

  int t = threadIdx.x, lane = t & 63, wave = t >> 6;
  int m16 = lane & 15, quad = lane >> 4;
  const float SCALE = 0.17677669529663687f;   // 1/sqrt(32)
  float extra = (float)(M - c);

  int qbase = q0 + wave * 32;
  frag8 qf[2];
#pragma unroll
  for (int qg = 0; qg < 2; ++qg) {
    int qrow = qbase + qg * 16 + m16;  // may exceed c: garbage, discarded at store
    qf[qg] = *(const frag8*)(qkv + (size_t)(st + qrow) * 768 + head * 32 + quad * 8);
  }

  f32x4 zz = {0.f, 0.f, 0.f, 0.f};
  f32x4 O[2][2];
  float lp[2] = {0.f, 0.f};
#pragma unroll
  for (int qg = 0; qg < 2; ++qg) { O[qg][0] = zz; O[qg][1] = zz; }

#if !HAS_MFMA16
  int sl0 = m16 + ((quad & 1) << 5);
  int sl1 = sl0 + 16;
#endif

  for (int kt = 0; kt < c; kt += KT) {
    {  // stage V^T tile: 128 keys x 32 d (OOB keys finite garbage, masked by p=0)
      int key = t >> 1, dh0 = (t & 1) * 16;
      const unsigned short* vp = qkv + (size_t)(st + kt + key) * 768 + 512 + head * 32 + dh0;
      ushort8 v0 = *(const ushort8*)vp;
      ushort8 v1 = *(const ushort8*)(vp + 8);
#pragma unroll
      for (int i = 0; i < 8; ++i) {
        Vt[dh0 + i][key] = v0[i];
        Vt[dh0 + 8 + i][key] = v1[i];
      }
    }
    __syncthreads();

#pragma unroll
    for (int sub = 0; sub < 4; ++sub) {
      int ks = kt + sub * 32;
      if (ks < c) {
        bool full = (ks + 32 <= c);          // wave-uniform
        frag8 kf[2];
#pragma unroll
        for (int kh = 0; kh < 2; ++kh) {
          int krow = ks + kh * 16 + m16;
          kf[kh] = *(const frag8*)(qkv + (size_t)(st + krow) * 768 + 256 + head * 32 + quad * 8);
        }
        unsigned pk[2][2][2];  // [qg][khalf][dword]  P^T, bf16-packed
#pragma unroll
        for (int qg = 0; qg < 2; ++qg)
#pragma unroll
          for (int kh = 0; kh < 2; ++kh) {
            f32x4 s = __builtin_amdgcn_mfma_f32_16x16x32_bf16(kf[kh], qf[qg], zz, 0, 0, 0);
            float p[4];
#pragma unroll
            for (int r = 0; r < 4; ++r) p[r] = __expf(s[r] * SCALE);
            if (!full) {
#pragma unroll
              for (int r = 0; r < 4; ++r)
                if (ks + kh * 16 + quad * 4 + r >= c) p[r] = 0.f;
            }
            lp[qg] += (p[0] + p[1]) + (p[2] + p[3]);
            pk[qg][kh][0] = pack2bf(p[0], p[1]);
            pk[qg][kh][1] = pack2bf(p[2], p[3]);
          }
#if HAS_MFMA16
        // PV: A = P^T chunk already in A-frag layout; B = V from Vt (8B reads)
        frag4 vb[2][2];
#pragma unroll
        for (int kh = 0; kh < 2; ++kh)
#pragma unroll
          for (int dh = 0; dh < 2; ++dh)
            vb[kh][dh] = *(const frag4*)&Vt[dh * 16 + m16][sub * 32 + kh * 16 + quad * 4];
#pragma unroll
        for (int qg = 0; qg < 2; ++qg) {
          frag4 pa0 = __builtin_bit_cast(frag4, uint2e{pk[qg][0][0], pk[qg][0][1]});
          frag4 pa1 = __builtin_bit_cast(frag4, uint2e{pk[qg][1][0], pk[qg][1][1]});
#pragma unroll
          for (int dh = 0; dh < 2; ++dh) {
            O[qg][dh] = __builtin_amdgcn_mfma_f32_16x16x16bf16_1k(pa0, vb[0][dh], O[qg][dh], 0, 0, 0);
            O[qg][dh] = __builtin_amdgcn_mfma_f32_16x16x16bf16_1k(pa1, vb[1][dh], O[qg][dh], 0, 0, 0);
          }
        }
#else
        frag8 vf[2];
#pragma unroll
        for (int dh = 0; dh < 2; ++dh)
          vf[dh] = *(const frag8*)&Vt[dh * 16 + m16][sub * 32 + quad * 8];
#pragma unroll
        for (int qg = 0; qg < 2; ++qg) {
          unsigned a0 = __shfl(pk[qg][0][0], sl0), a1 = __shfl(pk[qg][0][1], sl0);
          unsigned a2 = __shfl(pk[qg][0][0], sl1), a3 = __shfl(pk[qg][0][1], sl1);
          unsigned b0 = __shfl(pk[qg][1][0], sl0), b1 = __shfl(pk[qg][1][1], sl0);
          unsigned b2 = __shfl(pk[qg][1][0], sl1), b3 = __shfl(pk[qg][1][1], sl1);
          uint4 pw;
          pw.x = (quad < 2) ? a0 : b0;
          pw.y = (quad < 2) ? a1 : b1;
          pw.z = (quad < 2) ? a2 : b2;
          pw.w = (quad < 2) ? a3 : b3;
          frag8 pf = __builtin_bit_cast(frag8, pw);
#pragma unroll
          for (int dh = 0; dh < 2; ++dh)
            O[qg][dh] = __builtin_amdgcn_mfma_f32_16x16x32_bf16(pf, vf[dh], O[qg][dh], 0, 0, 0);
        }
#endif
      }
    }
    __syncthreads();
  }

  // lp per-lane partial (q = m16); reduce over quads
#pragma unroll
  for (int qg = 0; qg < 2; ++qg) {
    float v = lp[qg];
    v += __shfl_xor(v, 16);
    v += __shfl_xor(v, 32);
    lp[qg] = v;
  }

#pragma unroll
  for (int qg = 0; qg < 2; ++qg)
#pragma unroll
    for (int r = 0; r < 4; ++r) {
      int qrow = qbase + qg * 16 + quad * 4 + r;
      float lsum = __shfl(lp[qg], quad * 4 + r);  // l for this O-row
      if (qrow < c) {
        float inv = 1.f / (lsum + extra);
        unsigned short* op = ctx + (size_t)(st + qrow) * 256 + head * 32;
        op[m16] = f2bf(O[qg][0][r] * inv);
        op[16 + m16] = f2bf(O[qg][1][r] * inv);
      }
    }
}

// --------- BatchNorm apply+ReLU, bnp recomputed per-thread (L1-broadcast) ---------
__global__ __launch_bounds__(256) void k_bn_apply(const unsigned short* __restrict__ h,
                                                  const float* __restrict__ sums,
                                                  const float* __restrict__ gamma,
                                                  const float* __restrict__ beta,
                                                  float* __restrict__ out) {
  size_t i8 = ((size_t)blockIdx.x * 256 + threadIdx.x) * 8;
  int c0 = (int)(i8 & 255);
  ushort8 v = *(const ushort8*)(h + i8);
  float4 o0, o1;
  float res[8];
#pragma unroll
  for (int i = 0; i < 8; ++i) {
    int ch = c0 + i;
    float mean = sums[ch] * (1.0f / NN);
    float var = sums[256 + ch] * (1.0f / NN) - mean * mean;  // biased, ddof=0
    float sc = rsqrtf(var + 1e-5f) * gamma[ch];
    float sh = beta[ch] - mean * sc;
    res[i] = fmaxf(bf2f(v[i]) * sc + sh, 0.f);
  }
  o0.x = res[0]; o0.y = res[1]; o0.z = res[2]; o0.w = res[3];
  o1.x = res[4]; o1.y = res[5]; o1.z = res[6]; o1.w = res[7];
  *(float4*)(out + i8) = o0;
  *(float4*)(out + i8 + 4) = o1;
}

extern "C" void kernel_launch(void* const* d_in, const int* in_sizes, int n_in,
                              void* d_out, int out_size, void* d_ws, size_t ws_size,
                              hipStream_t stream) {
  const float* x      = (const float*)d_in[0];
  const float* spec   = (const float*)d_in[1];
  const float* Ws     = (const float*)d_in[2];
  const float* bs     = (const float*)d_in[3];
  const float* Win    = (const float*)d_in[4];
  const float* b_in   = (const float*)d_in[5];
  const float* Wout   = (const float*)d_in[6];
  const float* b_out  = (const float*)d_in[7];
  const float* gamma  = (const float*)d_in[8];
  const float* beta   = (const float*)d_in[9];
  const int* batch    = (const int*)d_in[10];   // harness passes integers as int32
  float* out = (float*)d_out;

  char* w = (char*)d_ws;
  size_t off = 0;
  auto alloc = [&](size_t bytes) -> void* {
    off = (off + 255) & ~(size_t)255;
    void* p = w + off; off += bytes; return p;
  };
  int* meta             = (int*)alloc(129 * sizeof(int));
  unsigned short* wst   = (unsigned short*)alloc((size_t)4 * 64 * 256 * 2);
  unsigned short* winb  = (unsigned short*)alloc((size_t)768 * 256 * 2);
  unsigned short* woutb = (unsigned short*)alloc((size_t)256 * 256 * 2);
  float* sums           = (float*)alloc(512 * 4);
  unsigned short* h     = (unsigned short*)alloc((size_t)NN * 256 * 2);
  unsigned short* qkv   = (unsigned short*)alloc((size_t)NN * 768 * 2);
  unsigned short* ctx   = (unsigned short*)alloc((size_t)NN * 256 * 2);
  unsigned short* hatt  = (unsigned short*)alloc((size_t)NN * 256 * 2);

  (void)hipMemsetAsync(sums, 0, 512 * 4, stream);
  k_prep<<<1280, 256, 0, stream>>>(Ws, Win, Wout, batch, wst, winb, woutb, meta);
  k_meta2<<<1, 64, 0, stream>>>(meta);
  k_scale<<<dim3(NN / SBM, 4), 256, 0, stream>>>(x, spec, wst, bs, h);
  k_lin<768, false, false><<<dim3(NN / SBM, 6), 256, 0, stream>>>(h, winb, b_in, qkv, nullptr);
  k_attn_mfma<<<dim3(NB * NHEAD, 8), 256, 0, stream>>>(qkv, meta, ctx);
  k_lin<256, false, true><<<dim3(NN / SBM, 2), 256, 0, stream>>>(ctx, woutb, b_out, hatt, sums);
  k_bn_apply<<<NN * 256 / 2048, 256, 0, stream>>>(hatt, sums, gamma, beta, out);
}

// Round 9
// 410.738 us; speedup vs baseline: 1.0814x; 1.0814x over previous
//
#include <hip/hip_runtime.h>

// SpectralConvLayer: per-scale linear (x+spectral)@Ws concat -> ragged MHA
// (no key-padding mask: padded keys contribute exp(0)=1 to denom) -> out-proj
// -> BatchNorm(batch stats) -> ReLU.
// Round 9: barrier-free GEMM k-loops (whole 64x256 B-panel resident in LDS,
// A-fragments loaded directly from global / built in registers for k_scale);
// BN stats moved to a dedicated coalesced kernel (atomics off the GEMM path).

typedef __attribute__((ext_vector_type(8))) short frag8;      // 8 bf16 (4 VGPR)
typedef __attribute__((ext_vector_type(4))) short frag4;      // 4 bf16 (2 VGPR)
typedef __attribute__((ext_vector_type(4))) float f32x4;
typedef __attribute__((ext_vector_type(8))) unsigned short ushort8;
typedef __attribute__((ext_vector_type(2))) unsigned int uint2e;

#define NN 32768
#define NB 64
#define CIN 256
#define COUT 256
#define NHEAD 8
#define HD 32

#define BM 128        // GEMM M-tile (4 waves x 32 rows)
#define LDB 264       // B-panel row stride in shorts (256 + 8 pad)
#define KT 128        // attention key-tile (V staging)

#if __has_builtin(__builtin_amdgcn_mfma_f32_16x16x16bf16_1k)
#define HAS_MFMA16 1
#else
#define HAS_MFMA16 0
#endif

__device__ inline unsigned short f2bf(float f) {
  unsigned u = __builtin_bit_cast(unsigned, f);
  u += 0x7FFFu + ((u >> 16) & 1u);          // RNE
  return (unsigned short)(u >> 16);
}
__device__ inline float bf2f(unsigned short h) {
  return __builtin_bit_cast(float, (unsigned)h << 16);
}
__device__ inline unsigned pack2bf(float a, float b) {
  return (unsigned)f2bf(a) | ((unsigned)f2bf(b) << 16);
}

// ---------------- prep (fp32->bf16 weights, Ws transposed) + batch boundaries ----
__global__ void k_prep(const float* __restrict__ Ws, const float* __restrict__ Win,
                       const float* __restrict__ Wout, const int* __restrict__ batch,
                       unsigned short* __restrict__ wst, unsigned short* __restrict__ winb,
                       unsigned short* __restrict__ woutb, int* __restrict__ meta) {
  int tid = blockIdx.x * 256 + threadIdx.x;
  if (tid < NN) {  // boundary detection on sorted batch -> starts
    int v = batch[tid];
    int prev = (tid == 0) ? -1 : batch[tid - 1];
    for (int bb = prev + 1; bb <= v; ++bb) meta[NB + bb] = tid;
  }
  if (tid < 4 * 64 * 256) {
    int s = tid >> 14, rem = tid & 16383, o = rem >> 8, i = rem & 255;
    wst[tid] = f2bf(Ws[((s * 256) + i) * 64 + o]);
  } else if (tid < 4 * 64 * 256 + 768 * 256) {
    int t2 = tid - 4 * 64 * 256;
    winb[t2] = f2bf(Win[t2]);
  } else if (tid < 4 * 64 * 256 + 768 * 256 + 256 * 256) {
    int t3 = tid - (4 * 64 * 256 + 768 * 256);
    woutb[t3] = f2bf(Wout[t3]);
  }
}
__global__ void k_meta2(int* __restrict__ meta) {
  __shared__ int mx[NB];
  int b = threadIdx.x;  // 64 threads
  int s = meta[NB + b];
  int e = (b == 63) ? NN : meta[NB + b + 1];
  meta[b] = e - s;
  mx[b] = e - s;
  __syncthreads();
  if (b == 0) {
    int m = 0;
    for (int j = 0; j < NB; ++j) m = max(m, mx[j]);
    meta[2 * NB] = m;
  }
}

// ---- stage a 64-row x 256-col bf16 B panel (Bt[n][k]) into LDS, 256 threads ----
__device__ inline void stage_Bpanel(const unsigned short* __restrict__ Wt,
                                    unsigned short (*Bs)[LDB], int t) {
  int n = t >> 2, seg = t & 3;   // 4 threads/row, 64 shorts each
  const unsigned short* src = Wt + (size_t)n * 256 + seg * 64;
#pragma unroll
  for (int i = 0; i < 8; ++i) {
    uint4 v = *(const uint4*)(src + i * 8);
    *(uint4*)&Bs[n][seg * 64 + i * 8] = v;
  }
}

// B-frag read: lane(n16=l&15, quad) -> Bs[ni*16+n16][k0 + quad*8]
// A-frag(16x16x32): lane(m16,quad) holds A[m16][k0+quad*8+j] — 16 B contiguous.
// C/D: lane holds D[quad*4+r][l&15]   (measured m89/m91)

// ---------------- scale-linear: h[n, s*64+o] = (x+spec_s)[n,:] @ Ws[s] + bs ----
// Barrier-free k-loop: A-fragments built in registers from global x+spec.
__global__ __launch_bounds__(256) void k_scale(const float* __restrict__ x,
                                               const float* __restrict__ spec,
                                               const unsigned short* __restrict__ wst,
                                               const float* __restrict__ bs,
                                               unsigned short* __restrict__ h) {
  __shared__ unsigned short Bs[64][LDB];
  int t = threadIdx.x, lane = t & 63, wave = t >> 6;
  int r0 = blockIdx.x * BM, s = blockIdx.y;
  int m16 = lane & 15, quad = lane >> 4;

  stage_Bpanel(wst + (size_t)s * 64 * 256, Bs, t);
  __syncthreads();   // the only barrier

  f32x4 z = {0.f, 0.f, 0.f, 0.f};
  f32x4 acc[2][4];
#pragma unroll
  for (int mi = 0; mi < 2; ++mi)
#pragma unroll
    for (int ni = 0; ni < 4; ++ni) acc[mi][ni] = z;

  const float* sb = spec + (size_t)s * NN * CIN;
#pragma unroll
  for (int kc = 0; kc < 8; ++kc) {        // 8 chunks of K=32
    int kb = kc * 32 + quad * 8;
    frag8 a[2];
#pragma unroll
    for (int mi = 0; mi < 2; ++mi) {
      size_t base = (size_t)(r0 + wave * 32 + mi * 16 + m16) * CIN + kb;
      float4 x0 = *(const float4*)(x + base);
      float4 x1 = *(const float4*)(x + base + 4);
      float4 s0 = *(const float4*)(sb + base);
      float4 s1 = *(const float4*)(sb + base + 4);
      uint4 u;
      u.x = pack2bf(x0.x + s0.x, x0.y + s0.y);
      u.y = pack2bf(x0.z + s0.z, x0.w + s0.w);
      u.z = pack2bf(x1.x + s1.x, x1.y + s1.y);
      u.w = pack2bf(x1.z + s1.z, x1.w + s1.w);
      a[mi] = __builtin_bit_cast(frag8, u);
    }
    frag8 b[4];
#pragma unroll
    for (int ni = 0; ni < 4; ++ni)
      b[ni] = *(const frag8*)&Bs[ni * 16 + m16][kc * 32 + quad * 8];
#pragma unroll
    for (int mi = 0; mi < 2; ++mi)
#pragma unroll
      for (int ni = 0; ni < 4; ++ni)
        acc[mi][ni] = __builtin_amdgcn_mfma_f32_16x16x32_bf16(a[mi], b[ni], acc[mi][ni], 0, 0, 0);
  }

#pragma unroll
  for (int mi = 0; mi < 2; ++mi)
#pragma unroll
    for (int ni = 0; ni < 4; ++ni) {
      int col = ni * 16 + m16;
      float bias = bs[s * 64 + col];
#pragma unroll
      for (int r = 0; r < 4; ++r) {
        int row = r0 + wave * 32 + mi * 16 + quad * 4 + r;
        h[(size_t)row * COUT + s * 64 + col] = f2bf(acc[mi][ni][r] + bias);
      }
    }
}

// ------- bf16 GEMM, BM=128/BN=64, barrier-free k-loop, A direct from global -------
template <int LDOUT>
__global__ __launch_bounds__(256) void k_lin(const unsigned short* __restrict__ A,
                                             const unsigned short* __restrict__ Wt,
                                             const float* __restrict__ bias,
                                             unsigned short* __restrict__ out) {
  __shared__ unsigned short Bs[64][LDB];
  int t = threadIdx.x, lane = t & 63, wave = t >> 6;
  int r0 = blockIdx.x * BM, c0 = blockIdx.y * 64;
  int m16 = lane & 15, quad = lane >> 4;

  stage_Bpanel(Wt + (size_t)c0 * 256, Bs, t);
  __syncthreads();   // the only barrier

  f32x4 z = {0.f, 0.f, 0.f, 0.f};
  f32x4 acc[2][4];
#pragma unroll
  for (int mi = 0; mi < 2; ++mi)
#pragma unroll
    for (int ni = 0; ni < 4; ++ni) acc[mi][ni] = z;

#pragma unroll
  for (int kc = 0; kc < 8; ++kc) {
    int kb = kc * 32 + quad * 8;
    frag8 a[2];
#pragma unroll
    for (int mi = 0; mi < 2; ++mi)
      a[mi] = *(const frag8*)(A + (size_t)(r0 + wave * 32 + mi * 16 + m16) * 256 + kb);
    frag8 b[4];
#pragma unroll
    for (int ni = 0; ni < 4; ++ni)
      b[ni] = *(const frag8*)&Bs[ni * 16 + m16][kc * 32 + quad * 8];
#pragma unroll
    for (int mi = 0; mi < 2; ++mi)
#pragma unroll
      for (int ni = 0; ni < 4; ++ni)
        acc[mi][ni] = __builtin_amdgcn_mfma_f32_16x16x32_bf16(a[mi], b[ni], acc[mi][ni], 0, 0, 0);
  }

#pragma unroll
  for (int mi = 0; mi < 2; ++mi)
#pragma unroll
    for (int ni = 0; ni < 4; ++ni) {
      int col = c0 + ni * 16 + m16;
      float bv = bias[col];
#pragma unroll
      for (int r = 0; r < 4; ++r) {
        int row = r0 + wave * 32 + mi * 16 + quad * 4 + r;
        out[(size_t)row * LDOUT + col] = f2bf(acc[mi][ni][r] + bv);
      }
    }
}

// ---------------- MFMA flash attention (unchanged from R7) ----------------
__global__ __launch_bounds__(256) void k_attn_mfma(const unsigned short* __restrict__ qkv,
                                                   const int* __restrict__ meta,
                                                   unsigned short* __restrict__ ctx) {
  int b = blockIdx.x >> 3, head = blockIdx.x & 7;
  int c = meta[b], st = meta[NB + b], M = meta[2 * NB];
  int q0 = blockIdx.y * 128;
  if (q0 >= c) return;

  __shared__ unsigned short Vt[32][KT + 8];   // V^T tile [d][key]

  int t = threadIdx.x, lane = t & 63, wave = t >> 6;
  int m16 = lane & 15, quad = lane >> 4;
  const float SCALE = 0.17677669529663687f;   // 1/sqrt(32)
  float extra = (float)(M - c);

  int qbase = q0 + wave * 32;
  frag8 qf[2];
#pragma unroll
  for (int qg = 0; qg < 2; ++qg) {
    int qrow = qbase + qg * 16 + m16;  // may exceed c: garbage, discarded at store
    qf[qg] = *(const frag8*)(qkv + (size_t)(st + qrow) * 768 + head * 32 + quad * 8);
  }

  f32x4 zz = {0.f, 0.f, 0.f, 0.f};
  f32x4 O[2][2];
  float lp[2] = {0.f, 0.f};
#pragma unroll
  for (int qg = 0; qg < 2; ++qg) { O[qg][0] = zz; O[qg][1] = zz; }

#if !HAS_MFMA16
  int sl0 = m16 + ((quad & 1) << 5);
  int sl1 = sl0 + 16;
#endif

  for (int kt = 0; kt < c; kt += KT) {
    {  // stage V^T tile: 128 keys x 32 d (OOB keys finite garbage, masked by p=0)
      int key = t >> 1, dh0 = (t & 1) * 16;
      const unsigned short* vp = qkv + (size_t)(st + kt + key) * 768 + 512 + head * 32 + dh0;
      ushort8 v0 = *(const ushort8*)vp;
      ushort8 v1 = *(const ushort8*)(vp + 8);
#pragma unroll
      for (int i = 0; i < 8; ++i) {
        Vt[dh0 + i][key] = v0[i];
        Vt[dh0 + 8 + i][key] = v1[i];
      }
    }
    __syncthreads();

#pragma unroll
    for (int sub = 0; sub < 4; ++sub) {
      int ks = kt + sub * 32;
      if (ks < c) {
        bool full = (ks + 32 <= c);          // wave-uniform
        frag8 kf[2];
#pragma unroll
        for (int kh = 0; kh < 2; ++kh) {
          int krow = ks + kh * 16 + m16;
          kf[kh] = *(const frag8*)(qkv + (size_t)(st + krow) * 768 + 256 + head * 32 + quad * 8);
        }
        unsigned pk[2][2][2];  // [qg][khalf][dword]  P^T, bf16-packed
#pragma unroll
        for (int qg = 0; qg < 2; ++qg)
#pragma unroll
          for (int kh = 0; kh < 2; ++kh) {
            f32x4 s = __builtin_amdgcn_mfma_f32_16x16x32_bf16(kf[kh], qf[qg], zz, 0, 0, 0);
            float p[4];
#pragma unroll
            for (int r = 0; r < 4; ++r) p[r] = __expf(s[r] * SCALE);
            if (!full) {
#pragma unroll
              for (int r = 0; r < 4; ++r)
                if (ks + kh * 16 + quad * 4 + r >= c) p[r] = 0.f;
            }
            lp[qg] += (p[0] + p[1]) + (p[2] + p[3]);
            pk[qg][kh][0] = pack2bf(p[0], p[1]);
            pk[qg][kh][1] = pack2bf(p[2], p[3]);
          }
#if HAS_MFMA16
        // PV: A = P^T chunk already in A-frag layout; B = V from Vt (8B reads)
        frag4 vb[2][2];
#pragma unroll
        for (int kh = 0; kh < 2; ++kh)
#pragma unroll
          for (int dh = 0; dh < 2; ++dh)
            vb[kh][dh] = *(const frag4*)&Vt[dh * 16 + m16][sub * 32 + kh * 16 + quad * 4];
#pragma unroll
        for (int qg = 0; qg < 2; ++qg) {
          frag4 pa0 = __builtin_bit_cast(frag4, uint2e{pk[qg][0][0], pk[qg][0][1]});
          frag4 pa1 = __builtin_bit_cast(frag4, uint2e{pk[qg][1][0], pk[qg][1][1]});
#pragma unroll
          for (int dh = 0; dh < 2; ++dh) {
            O[qg][dh] = __builtin_amdgcn_mfma_f32_16x16x16bf16_1k(pa0, vb[0][dh], O[qg][dh], 0, 0, 0);
            O[qg][dh] = __builtin_amdgcn_mfma_f32_16x16x16bf16_1k(pa1, vb[1][dh], O[qg][dh], 0, 0, 0);
          }
        }
#else
        frag8 vf[2];
#pragma unroll
        for (int dh = 0; dh < 2; ++dh)
          vf[dh] = *(const frag8*)&Vt[dh * 16 + m16][sub * 32 + quad * 8];
#pragma unroll
        for (int qg = 0; qg < 2; ++qg) {
          unsigned a0 = __shfl(pk[qg][0][0], sl0), a1 = __shfl(pk[qg][0][1], sl0);
          unsigned a2 = __shfl(pk[qg][0][0], sl1), a3 = __shfl(pk[qg][0][1], sl1);
          unsigned b0 = __shfl(pk[qg][1][0], sl0), b1 = __shfl(pk[qg][1][1], sl0);
          unsigned b2 = __shfl(pk[qg][1][0], sl1), b3 = __shfl(pk[qg][1][1], sl1);
          uint4 pw;
          pw.x = (quad < 2) ? a0 : b0;
          pw.y = (quad < 2) ? a1 : b1;
          pw.z = (quad < 2) ? a2 : b2;
          pw.w = (quad < 2) ? a3 : b3;
          frag8 pf = __builtin_bit_cast(frag8, pw);
#pragma unroll
          for (int dh = 0; dh < 2; ++dh)
            O[qg][dh] = __builtin_amdgcn_mfma_f32_16x16x32_bf16(pf, vf[dh], O[qg][dh], 0, 0, 0);
        }
#endif
      }
    }
    __syncthreads();
  }

  // lp per-lane partial (q = m16); reduce over quads
#pragma unroll
  for (int qg = 0; qg < 2; ++qg) {
    float v = lp[qg];
    v += __shfl_xor(v, 16);
    v += __shfl_xor(v, 32);
    lp[qg] = v;
  }

#pragma unroll
  for (int qg = 0; qg < 2; ++qg)
#pragma unroll
    for (int r = 0; r < 4; ++r) {
      int qrow = qbase + qg * 16 + quad * 4 + r;
      float lsum = __shfl(lp[qg], quad * 4 + r);  // l for this O-row
      if (qrow < c) {
        float inv = 1.f / (lsum + extra);
        unsigned short* op = ctx + (size_t)(st + qrow) * 256 + head * 32;
        op[m16] = f2bf(O[qg][0][r] * inv);
        op[16 + m16] = f2bf(O[qg][1][r] * inv);
      }
    }
}

// ---- BN stats: thread = channel, fully coalesced rows, register accumulation ----
__global__ __launch_bounds__(256) void k_stats(const unsigned short* __restrict__ h,
                                               float* __restrict__ sums) {
  int c = threadIdx.x;
  int r0 = blockIdx.x * 64;
  float s = 0.f, s2 = 0.f;
#pragma unroll 8
  for (int r = 0; r < 64; ++r) {
    float v = bf2f(h[(size_t)(r0 + r) * 256 + c]);
    s += v; s2 += v * v;
  }
  atomicAdd(&sums[c], s);
  atomicAdd(&sums[256 + c], s2);
}

// --------- BatchNorm apply+ReLU, bnp recomputed per-thread (L1-broadcast) ---------
__global__ __launch_bounds__(256) void k_bn_apply(const unsigned short* __restrict__ h,
                                                  const float* __restrict__ sums,
                                                  const float* __restrict__ gamma,
                                                  const float* __restrict__ beta,
                                                  float* __restrict__ out) {
  size_t i8 = ((size_t)blockIdx.x * 256 + threadIdx.x) * 8;
  int c0 = (int)(i8 & 255);
  ushort8 v = *(const ushort8*)(h + i8);
  float4 o0, o1;
  float res[8];
#pragma unroll
  for (int i = 0; i < 8; ++i) {
    int ch = c0 + i;
    float mean = sums[ch] * (1.0f / NN);
    float var = sums[256 + ch] * (1.0f / NN) - mean * mean;  // biased, ddof=0
    float sc = rsqrtf(var + 1e-5f) * gamma[ch];
    float sh = beta[ch] - mean * sc;
    res[i] = fmaxf(bf2f(v[i]) * sc + sh, 0.f);
  }
  o0.x = res[0]; o0.y = res[1]; o0.z = res[2]; o0.w = res[3];
  o1.x = res[4]; o1.y = res[5]; o1.z = res[6]; o1.w = res[7];
  *(float4*)(out + i8) = o0;
  *(float4*)(out + i8 + 4) = o1;
}

extern "C" void kernel_launch(void* const* d_in, const int* in_sizes, int n_in,
                              void* d_out, int out_size, void* d_ws, size_t ws_size,
                              hipStream_t stream) {
  const float* x      = (const float*)d_in[0];
  const float* spec   = (const float*)d_in[1];
  const float* Ws     = (const float*)d_in[2];
  const float* bs     = (const float*)d_in[3];
  const float* Win    = (const float*)d_in[4];
  const float* b_in   = (const float*)d_in[5];
  const float* Wout   = (const float*)d_in[6];
  const float* b_out  = (const float*)d_in[7];
  const float* gamma  = (const float*)d_in[8];
  const float* beta   = (const float*)d_in[9];
  const int* batch    = (const int*)d_in[10];   // harness passes integers as int32
  float* out = (float*)d_out;

  char* w = (char*)d_ws;
  size_t off = 0;
  auto alloc = [&](size_t bytes) -> void* {
    off = (off + 255) & ~(size_t)255;
    void* p = w + off; off += bytes; return p;
  };
  int* meta             = (int*)alloc(129 * sizeof(int));
  unsigned short* wst   = (unsigned short*)alloc((size_t)4 * 64 * 256 * 2);
  unsigned short* winb  = (unsigned short*)alloc((size_t)768 * 256 * 2);
  unsigned short* woutb = (unsigned short*)alloc((size_t)256 * 256 * 2);
  float* sums           = (float*)alloc(512 * 4);
  unsigned short* h     = (unsigned short*)alloc((size_t)NN * 256 * 2);
  unsigned short* qkv   = (unsigned short*)alloc((size_t)NN * 768 * 2);
  unsigned short* ctx   = (unsigned short*)alloc((size_t)NN * 256 * 2);
  unsigned short* hatt  = (unsigned short*)alloc((size_t)NN * 256 * 2);

  (void)hipMemsetAsync(sums, 0, 512 * 4, stream);
  k_prep<<<1280, 256, 0, stream>>>(Ws, Win, Wout, batch, wst, winb, woutb, meta);
  k_meta2<<<1, 64, 0, stream>>>(meta);
  k_scale<<<dim3(NN / BM, 4), 256, 0, stream>>>(x, spec, wst, bs, h);
  k_lin<768><<<dim3(NN / BM, 12), 256, 0, stream>>>(h, winb, b_in, qkv);
  k_attn_mfma<<<dim3(NB * NHEAD, 8), 256, 0, stream>>>(qkv, meta, ctx);
  k_lin<256><<<dim3(NN / BM, 4), 256, 0, stream>>>(ctx, woutb, b_out, hatt);
  k_stats<<<NN / 64, 256, 0, stream>>>(hatt, sums);
  k_bn_apply<<<NN * 256 / 2048, 256, 0, stream>>>(hatt, sums, gamma, beta, out);
}